// Round 1
// baseline (265.953 us; speedup 1.0000x reference)
//
#include <hip/hip_runtime.h>
#include <math.h>

// Problem constants (B=2, L=2048, D=512, N=64) -> M = B*L = 4096 tokens.
#define DDIM 512
#define NDIM 64

// y[t,d] = x[t,d] * softplus((x@W1 + b1)[t,d]) * s[t]
// s[t]   = dot(x_t@W2 + b2, x_t@W3 + b3)
// (dA = exp(delta A) term multiplies h=0, contributes exactly zero.)

__device__ __forceinline__ float softplusf(float v) {
    // stable log1p(exp(v)); for v>20, log1p(exp(v)) == v to fp32 precision
    return (v > 20.0f) ? v : log1pf(__expf(v));
}

// ---------------------------------------------------------------------------
// Kernel A: s[t] for all tokens.  Grid: M/16 blocks x 256 threads.
// Each wave (64 lanes) owns 4 tokens; lane n owns state-column n (N=64).
// ---------------------------------------------------------------------------
__global__ __launch_bounds__(256) void compute_s_kernel(
    const float* __restrict__ x,
    const float* __restrict__ W2, const float* __restrict__ b2,
    const float* __restrict__ W3, const float* __restrict__ b3,
    float* __restrict__ s_out)
{
    __shared__ float xs[16][68];          // 16 tokens x 64 k (pad row to 68)
    const int tid = threadIdx.x;
    const int tb  = blockIdx.x * 16;
    const int n   = tid & 63;             // state column
    const int wv  = tid >> 6;             // wave id 0..3 -> token group
    const int lr  = tid >> 4;             // load row 0..15
    const int lc  = (tid & 15) * 4;       // load col 0..60

    float accB[4], accC[4];
    const float b2n = b2[n], b3n = b3[n];
#pragma unroll
    for (int i = 0; i < 4; ++i) { accB[i] = b2n; accC[i] = b3n; }

    for (int kc = 0; kc < DDIM; kc += 64) {
        float4 v = *(const float4*)(x + (size_t)(tb + lr) * DDIM + kc + lc);
        xs[lr][lc + 0] = v.x; xs[lr][lc + 1] = v.y;
        xs[lr][lc + 2] = v.z; xs[lr][lc + 3] = v.w;
        __syncthreads();
#pragma unroll 8
        for (int kk = 0; kk < 64; ++kk) {
            float w2v = W2[(size_t)(kc + kk) * NDIM + n];
            float w3v = W3[(size_t)(kc + kk) * NDIM + n];
#pragma unroll
            for (int i = 0; i < 4; ++i) {
                float xv = xs[wv * 4 + i][kk];   // broadcast within wave
                accB[i] = fmaf(xv, w2v, accB[i]);
                accC[i] = fmaf(xv, w3v, accC[i]);
            }
        }
        __syncthreads();
    }

#pragma unroll
    for (int i = 0; i < 4; ++i) {
        float p = accB[i] * accC[i];
        // reduce across the 64 lanes (over n)
        for (int off = 32; off > 0; off >>= 1)
            p += __shfl_xor(p, off, 64);
        if (n == 0) s_out[tb + wv * 4 + i] = p;
    }
}

// ---------------------------------------------------------------------------
// Kernel B: fused GEMM (x @ W1) + bias + softplus + x*s epilogue.
// Tile: BM=128 tokens x BN=64 d-outputs, BK=32.  256 threads, 8x4 micro-tile.
// Grid: (DDIM/BN, M/BM) = (8, 32) = 256 blocks -> 1 block/CU.
// ---------------------------------------------------------------------------
#define BM 128
#define BN 64
#define BK 32
#define SX 132   // BM + 4 pad (keeps 16B alignment: 132*4 % 16 == 0)
#define SW 68    // BN + 4 pad

__global__ __launch_bounds__(256) void fused_gemm_kernel(
    const float* __restrict__ x, const float* __restrict__ W1,
    const float* __restrict__ b1, const float* __restrict__ s_in,
    float* __restrict__ y)
{
    __shared__ float xT[BK][SX];   // [k][token]  (transposed x chunk)
    __shared__ float wS[BK][SW];   // [k][d]

    const int tid = threadIdx.x;
    const int tx  = tid & 15;      // d-group: 4 outputs each
    const int ty  = tid >> 4;      // token-group: 8 tokens each
    const int db  = blockIdx.x * BN;
    const int tb  = blockIdx.y * BM;

    float acc[8][4];
#pragma unroll
    for (int i = 0; i < 8; ++i)
#pragma unroll
        for (int j = 0; j < 4; ++j) acc[i][j] = 0.0f;

    const int xc4 = (tid & 7) * 4;   // k-offset within chunk for x staging
    const int xr0 = tid >> 3;        // 0..31
    const int wc4 = (tid & 15) * 4;  // d-offset for W staging
    const int wr0 = tid >> 4;        // 0..15

    for (int kc = 0; kc < DDIM; kc += BK) {
        // stage x chunk transposed: xT[k][token]
#pragma unroll
        for (int p = 0; p < 4; ++p) {
            int r = xr0 + 32 * p;    // token row 0..127
            float4 v = *(const float4*)(x + (size_t)(tb + r) * DDIM + kc + xc4);
            xT[xc4 + 0][r] = v.x; xT[xc4 + 1][r] = v.y;
            xT[xc4 + 2][r] = v.z; xT[xc4 + 3][r] = v.w;
        }
        // stage W1 chunk: wS[k][d]
#pragma unroll
        for (int p = 0; p < 2; ++p) {
            int r = wr0 + 16 * p;    // k row 0..31
            float4 v = *(const float4*)(W1 + (size_t)(kc + r) * DDIM + db + wc4);
            *(float4*)&wS[r][wc4] = v;
        }
        __syncthreads();

#pragma unroll 8
        for (int kk = 0; kk < BK; ++kk) {
            float4 a0 = *(const float4*)&xT[kk][ty * 8];
            float4 a1 = *(const float4*)&xT[kk][ty * 8 + 4];
            float4 b  = *(const float4*)&wS[kk][tx * 4];
            float av[8] = {a0.x, a0.y, a0.z, a0.w, a1.x, a1.y, a1.z, a1.w};
            float bv[4] = {b.x, b.y, b.z, b.w};
#pragma unroll
            for (int i = 0; i < 8; ++i)
#pragma unroll
                for (int j = 0; j < 4; ++j)
                    acc[i][j] = fmaf(av[i], bv[j], acc[i][j]);
        }
        __syncthreads();
    }

    // epilogue: y = x * softplus(acc + b1) * s
    float4 b1v = *(const float4*)(b1 + db + tx * 4);
#pragma unroll
    for (int i = 0; i < 8; ++i) {
        int t = tb + ty * 8 + i;
        float st = s_in[t];
        float4 xv = *(const float4*)(x + (size_t)t * DDIM + db + tx * 4);
        float4 o;
        o.x = xv.x * softplusf(acc[i][0] + b1v.x) * st;
        o.y = xv.y * softplusf(acc[i][1] + b1v.y) * st;
        o.z = xv.z * softplusf(acc[i][2] + b1v.z) * st;
        o.w = xv.w * softplusf(acc[i][3] + b1v.w) * st;
        *(float4*)(y + (size_t)t * DDIM + db + tx * 4) = o;
    }
}

// ---------------------------------------------------------------------------
extern "C" void kernel_launch(void* const* d_in, const int* in_sizes, int n_in,
                              void* d_out, int out_size, void* d_ws, size_t ws_size,
                              hipStream_t stream)
{
    (void)n_in; (void)out_size; (void)ws_size;
    const float* x  = (const float*)d_in[0];
    const float* W1 = (const float*)d_in[1];
    const float* b1 = (const float*)d_in[2];
    const float* W2 = (const float*)d_in[3];
    const float* b2 = (const float*)d_in[4];
    const float* W3 = (const float*)d_in[5];
    const float* b3 = (const float*)d_in[6];
    // d_in[7] = A is unused: exp(delta*A) multiplies h=0 -> contributes 0.

    float* y    = (float*)d_out;
    float* s_ws = (float*)d_ws;            // M floats of scratch

    const int M = in_sizes[0] / DDIM;      // 4096 tokens

    compute_s_kernel<<<M / 16, 256, 0, stream>>>(x, W2, b2, W3, b3, s_ws);
    fused_gemm_kernel<<<dim3(DDIM / BN, M / BM), 256, 0, stream>>>(x, W1, b1, s_ws, y);
}

// Round 2
// 120.321 us; speedup vs baseline: 2.2104x; 2.2104x over previous
//
#include <hip/hip_runtime.h>
#include <math.h>

// Problem: B=2, L=2048, D=512, N=64 -> M = 4096 tokens.
//   y[t,d] = x[t,d] * softplus((x@W1+b1)[t,d]) * s[t]
//   s[t]   = dot(x_t@W2+b2, x_t@W3+b3)
//   (exp(delta*A) multiplies h=0 -> contributes exactly zero; A unused.)
#define DDIM 512
#define NDIM 64

typedef _Float16 f16;
typedef _Float16 f16x4 __attribute__((ext_vector_type(4)));
typedef _Float16 f16x8 __attribute__((ext_vector_type(8)));
typedef float f32x4 __attribute__((ext_vector_type(4)));

__device__ __forceinline__ float softplusf(float v) {
    return (v > 20.0f) ? v : log1pf(__expf(v));
}

// ---------------------------------------------------------------------------
// Kernel 1: s[t] via f16 MFMA.  BM=16 tokens/block, N=128 (W2|W3), K=512.
// Grid: 256 blocks x 256 threads (4 waves; wave w owns n-tiles 2w, 2w+1).
// mfma_f32_16x16x32_f16 layouts:
//   A[m][k]: m=lane&15, k=(lane>>4)*8+j   (8 f16 contiguous in k)
//   B[k][n]: n=lane&15, k=(lane>>4)*8+j
//   C/D:     col=lane&15, row=(lane>>4)*4+reg
// ---------------------------------------------------------------------------
__global__ __launch_bounds__(256) void s_kernel(
    const float* __restrict__ x,
    const float* __restrict__ W2, const float* __restrict__ b2,
    const float* __restrict__ W3, const float* __restrict__ b3,
    float* __restrict__ s_out)
{
    __shared__ f16 xs[16][32];       // [token][k]
    __shared__ f16 w23[128][40];     // [n'][k]  n'<64: W2, n'>=64: W3 (pad 40)
    __shared__ float bc[16][132];    // [token][n'] f32 result + bias

    const int tid  = threadIdx.x;
    const int tb   = blockIdx.x * 16;
    const int lane = tid & 63;
    const int wv   = tid >> 6;
    const int q    = lane >> 4;
    const int l15  = lane & 15;

    f32x4 acc[2];
#pragma unroll
    for (int i = 0; i < 2; ++i) acc[i] = (f32x4){0.f, 0.f, 0.f, 0.f};

    const int wk0 = tid >> 4;          // 0..15
    const int wn4 = (tid & 15) * 4;    // 0..60

    for (int kc = 0; kc < DDIM; kc += 32) {
        if (tid < 128) {
            int token = tid >> 3, k4 = (tid & 7) * 4;
            float4 v = *(const float4*)(x + (size_t)(tb + token) * DDIM + kc + k4);
            f16x4 h = {(f16)v.x, (f16)v.y, (f16)v.z, (f16)v.w};
            *(f16x4*)&xs[token][k4] = h;
        }
#pragma unroll
        for (int p = 0; p < 2; ++p) {
            int k = wk0 + 16 * p;
            float4 v2 = *(const float4*)(W2 + (size_t)(kc + k) * NDIM + wn4);
            w23[wn4 + 0][k] = (f16)v2.x; w23[wn4 + 1][k] = (f16)v2.y;
            w23[wn4 + 2][k] = (f16)v2.z; w23[wn4 + 3][k] = (f16)v2.w;
            float4 v3 = *(const float4*)(W3 + (size_t)(kc + k) * NDIM + wn4);
            w23[64 + wn4 + 0][k] = (f16)v3.x; w23[64 + wn4 + 1][k] = (f16)v3.y;
            w23[64 + wn4 + 2][k] = (f16)v3.z; w23[64 + wn4 + 3][k] = (f16)v3.w;
        }
        __syncthreads();

        f16x8 a = *(const f16x8*)&xs[l15][q * 8];
#pragma unroll
        for (int nt = 0; nt < 2; ++nt) {
            int n = (wv * 2 + nt) * 16 + l15;
            f16x8 b = *(const f16x8*)&w23[n][q * 8];
            acc[nt] = __builtin_amdgcn_mfma_f32_16x16x32_f16(a, b, acc[nt], 0, 0, 0);
        }
        __syncthreads();
    }

    // spill BC (+bias) to LDS
#pragma unroll
    for (int nt = 0; nt < 2; ++nt) {
        int n = (wv * 2 + nt) * 16 + l15;
        float bias = (n < 64) ? b2[n] : b3[n - 64];
#pragma unroll
        for (int r = 0; r < 4; ++r)
            bc[q * 4 + r][n] = acc[nt][r] + bias;
    }
    __syncthreads();

    // s[t] = sum_n B[t][n] * C[t][n]
    int token = tid >> 4, j0 = (tid & 15) * 4;
    float p = 0.f;
#pragma unroll
    for (int i = 0; i < 4; ++i)
        p += bc[token][j0 + i] * bc[token][64 + j0 + i];
    p += __shfl_xor(p, 1); p += __shfl_xor(p, 2);
    p += __shfl_xor(p, 4); p += __shfl_xor(p, 8);
    if ((tid & 15) == 0) s_out[tb + token] = p;
}

// ---------------------------------------------------------------------------
// Kernel 2: y = x * softplus(x@W1 + b1) * s  via f16 MFMA.
// Tile BM=128 x BN=64, BK=32.  Grid (8, 32) = 256 blocks x 256 threads.
// Wave w owns tokens [w*32, w*32+32) x all 64 n  (2 row-tiles x 4 n-tiles).
// ---------------------------------------------------------------------------
__global__ __launch_bounds__(256) void y_kernel(
    const float* __restrict__ x, const float* __restrict__ W1,
    const float* __restrict__ b1, const float* __restrict__ s_in,
    float* __restrict__ y)
{
    __shared__ f16 xs[128][32];      // [token][k]
    __shared__ f16 ws[64][40];       // [n][k]   (pad 40)

    const int tid  = threadIdx.x;
    const int lane = tid & 63;
    const int wv   = tid >> 6;
    const int q    = lane >> 4;
    const int l15  = lane & 15;
    const int db   = blockIdx.x * 64;
    const int tb   = blockIdx.y * 128;

    f32x4 acc[2][4];
#pragma unroll
    for (int i = 0; i < 2; ++i)
#pragma unroll
        for (int j = 0; j < 4; ++j) acc[i][j] = (f32x4){0.f, 0.f, 0.f, 0.f};

    const int xt0 = tid >> 3;          // 0..31
    const int xk4 = (tid & 7) * 4;     // 0..28
    const int wk0 = tid >> 4;          // 0..15
    const int wn4 = (tid & 15) * 4;    // 0..60

    for (int kc = 0; kc < DDIM; kc += 32) {
#pragma unroll
        for (int p = 0; p < 4; ++p) {
            int token = xt0 + 32 * p;
            float4 v = *(const float4*)(x + (size_t)(tb + token) * DDIM + kc + xk4);
            f16x4 h = {(f16)v.x, (f16)v.y, (f16)v.z, (f16)v.w};
            *(f16x4*)&xs[token][xk4] = h;
        }
#pragma unroll
        for (int p = 0; p < 2; ++p) {
            int k = wk0 + 16 * p;
            float4 v = *(const float4*)(W1 + (size_t)(kc + k) * DDIM + db + wn4);
            ws[wn4 + 0][k] = (f16)v.x; ws[wn4 + 1][k] = (f16)v.y;
            ws[wn4 + 2][k] = (f16)v.z; ws[wn4 + 3][k] = (f16)v.w;
        }
        __syncthreads();

        f16x8 a[2], b[4];
#pragma unroll
        for (int rt = 0; rt < 2; ++rt)
            a[rt] = *(const f16x8*)&xs[wv * 32 + rt * 16 + l15][q * 8];
#pragma unroll
        for (int nt = 0; nt < 4; ++nt)
            b[nt] = *(const f16x8*)&ws[nt * 16 + l15][q * 8];
#pragma unroll
        for (int rt = 0; rt < 2; ++rt)
#pragma unroll
            for (int nt = 0; nt < 4; ++nt)
                acc[rt][nt] = __builtin_amdgcn_mfma_f32_16x16x32_f16(a[rt], b[nt], acc[rt][nt], 0, 0, 0);
        __syncthreads();
    }

    // epilogue: y = x * softplus(acc + b1) * s
    float b1v[4];
#pragma unroll
    for (int nt = 0; nt < 4; ++nt) b1v[nt] = b1[db + nt * 16 + l15];

#pragma unroll
    for (int rt = 0; rt < 2; ++rt) {
#pragma unroll
        for (int r = 0; r < 4; ++r) {
            int token = tb + wv * 32 + rt * 16 + q * 4 + r;
            float st = s_in[token];
#pragma unroll
            for (int nt = 0; nt < 4; ++nt) {
                int d = db + nt * 16 + l15;
                float v = softplusf(acc[rt][nt][r] + b1v[nt]);
                y[(size_t)token * DDIM + d] = x[(size_t)token * DDIM + d] * v * st;
            }
        }
    }
}

// ---------------------------------------------------------------------------
extern "C" void kernel_launch(void* const* d_in, const int* in_sizes, int n_in,
                              void* d_out, int out_size, void* d_ws, size_t ws_size,
                              hipStream_t stream)
{
    (void)n_in; (void)out_size; (void)ws_size;
    const float* x  = (const float*)d_in[0];
    const float* W1 = (const float*)d_in[1];
    const float* b1 = (const float*)d_in[2];
    const float* W2 = (const float*)d_in[3];
    const float* b2 = (const float*)d_in[4];
    const float* W3 = (const float*)d_in[5];
    const float* b3 = (const float*)d_in[6];
    // d_in[7] = A unused (multiplies h=0)

    float* y    = (float*)d_out;
    float* s_ws = (float*)d_ws;          // M floats

    const int M = in_sizes[0] / DDIM;    // 4096

    s_kernel<<<M / 16, 256, 0, stream>>>(x, W2, b2, W3, b3, s_ws);
    y_kernel<<<dim3(DDIM / 64, M / 128), 256, 0, stream>>>(x, W1, b1, s_ws, y);
}

// Round 3
// 102.229 us; speedup vs baseline: 2.6015x; 1.1770x over previous
//
#include <hip/hip_runtime.h>
#include <math.h>

// B=2, L=2048, D=512, N=64 -> M=4096 tokens.
//   y[t,d] = x[t,d] * softplus((x@W1+b1)[t,d]) * s[t]
//   s[t]   = dot(x_t@W2+b2, x_t@W3+b3)
//   exp(delta*A) multiplies h=0 -> contributes zero; A unused.
#define DDIM 512
#define MTOK 4096

typedef _Float16 f16;
typedef _Float16 f16x4 __attribute__((ext_vector_type(4)));
typedef _Float16 f16x8 __attribute__((ext_vector_type(8)));
typedef float f32x4 __attribute__((ext_vector_type(4)));

__device__ __forceinline__ float softplusf(float v) {
    return (v > 20.0f) ? v : log1pf(__expf(v));
}

// async global->LDS, 16B per lane; LDS dest = wave-uniform base + lane*16
__device__ __forceinline__ void async_load16(const void* g, void* l) {
    __builtin_amdgcn_global_load_lds(
        (const __attribute__((address_space(1))) void*)g,
        (__attribute__((address_space(3))) void*)l, 16, 0, 0);
}

// ---------------------------------------------------------------------------
// Prep: convert x -> xh (f16 [4096][512]) ; transpose-convert
//   W1 (512x512) -> w1t[n][k] f16 ; W2,W3 (512x64) -> w23[n'][k] (n'<64: W2T,
//   n'>=64: W3T).  Grid: 2048 convert blocks + 80 transpose blocks.
// ---------------------------------------------------------------------------
__global__ __launch_bounds__(256) void prep_kernel(
    const float* __restrict__ x,  const float* __restrict__ W1,
    const float* __restrict__ W2, const float* __restrict__ W3,
    f16* __restrict__ xh, f16* __restrict__ w1t, f16* __restrict__ w23)
{
    const int tid = threadIdx.x;
    if (blockIdx.x < 2048) {                       // ---- convert x
        size_t gid = ((size_t)blockIdx.x * 256 + tid) * 4;
        float4 v = *(const float4*)(x + gid);
        f16x4 h = {(f16)v.x, (f16)v.y, (f16)v.z, (f16)v.w};
        *(f16x4*)(xh + gid) = h;
        return;
    }
    // ---- transpose-convert one 64x64 tile
    __shared__ f16 lt[64][72];
    int b2 = blockIdx.x - 2048;                    // 0..79
    const float* src; f16* dst; int srcRS;
    if (b2 < 64) {          // W1 tile (kt, nt)
        int kt = b2 >> 3, nt = b2 & 7;
        src = W1 + (size_t)(kt * 64) * DDIM + nt * 64; srcRS = DDIM;
        dst = w1t + (size_t)(nt * 64) * DDIM + kt * 64;
    } else if (b2 < 72) {   // W2 tile kt
        int kt = b2 - 64;
        src = W2 + (size_t)(kt * 64) * 64; srcRS = 64;
        dst = w23 + kt * 64;
    } else {                // W3 tile kt
        int kt = b2 - 72;
        src = W3 + (size_t)(kt * 64) * 64; srcRS = 64;
        dst = w23 + (size_t)64 * DDIM + kt * 64;
    }
    int r  = tid >> 2;          // 0..63 source row
    int cg = tid & 3;           // col group
#pragma unroll
    for (int p = 0; p < 4; ++p) {
        float4 v = *(const float4*)(src + (size_t)r * srcRS + cg * 16 + p * 4);
        lt[cg * 16 + p * 4 + 0][r] = (f16)v.x;
        lt[cg * 16 + p * 4 + 1][r] = (f16)v.y;
        lt[cg * 16 + p * 4 + 2][r] = (f16)v.z;
        lt[cg * 16 + p * 4 + 3][r] = (f16)v.w;
    }
    __syncthreads();
    // write transposed rows: dst[r][k] contiguous
    *(f16x8*)(dst + (size_t)r * DDIM + cg * 16)     = *(const f16x8*)&lt[r][cg * 16];
    *(f16x8*)(dst + (size_t)r * DDIM + cg * 16 + 8) = *(const f16x8*)&lt[r][cg * 16 + 8];
}

// ---------------------------------------------------------------------------
// s_kernel: 32 tokens/block, n'=128 (B|C), K=512, BK=64, double-buffered.
// 256 threads = 4 waves.  Wave w owns n-tiles (w, w+4) -> B/C pair resident.
// LDS slabs are stored in MFMA-fragment order: slab = 64 lanes x 16B,
// lane L=(q*16+m): element (row m, k = kk*32 + q*8 .. +7).
// ---------------------------------------------------------------------------
#define S_BUF 20480   // 4 x-slabs (4KB) + 16 w-slabs (16KB)
__global__ __launch_bounds__(256) void s_kernel(
    const f16* __restrict__ xh, const f16* __restrict__ w23,
    const float* __restrict__ b2, const float* __restrict__ b3,
    float* __restrict__ s_out)
{
    __shared__ __align__(16) char smem[2 * S_BUF + 512];
    float* sred = (float*)(smem + 2 * S_BUF);      // [4][32]

    const int tid  = threadIdx.x;
    const int wv   = tid >> 6;
    const int lane = tid & 63;
    const int q    = lane >> 4;
    const int l15  = lane & 15;
    const int tb   = blockIdx.x * 32;

    f32x4 acc[2][2];
#pragma unroll
    for (int m = 0; m < 2; ++m)
#pragma unroll
        for (int p = 0; p < 2; ++p) acc[m][p] = (f32x4){0.f, 0.f, 0.f, 0.f};

    // wave wv stages slabs {5wv .. 5wv+4}
    auto issue = [&](int buf, int kc) {
#pragma unroll
        for (int j = 0; j < 5; ++j) {
            int id = wv * 5 + j;
            const f16* g; int off;
            if (id < 4) {
                int mt = id >> 1, kk = id & 1;
                g = xh + (size_t)(tb + mt * 16 + l15) * DDIM + kc + kk * 32 + q * 8;
                off = id * 1024;
            } else {
                int t = id - 4; int nt = t >> 1, kk = t & 1;
                g = w23 + (size_t)(nt * 16 + l15) * DDIM + kc + kk * 32 + q * 8;
                off = 4096 + t * 1024;
            }
            async_load16(g, smem + buf * S_BUF + off);
        }
    };

    issue(0, 0);
    for (int it = 0; it < 8; ++it) {
        __syncthreads();
        if (it + 1 < 8) issue((it + 1) & 1, (it + 1) * 64);
        const char* xb = smem + (it & 1) * S_BUF;
        const char* wb = xb + 4096;
#pragma unroll
        for (int kk = 0; kk < 2; ++kk) {
            f16x8 a0 = *(const f16x8*)(xb + (0 * 2 + kk) * 1024 + lane * 16);
            f16x8 a1 = *(const f16x8*)(xb + (1 * 2 + kk) * 1024 + lane * 16);
            f16x8 bB = *(const f16x8*)(wb + ((wv    ) * 2 + kk) * 1024 + lane * 16);
            f16x8 bC = *(const f16x8*)(wb + ((wv + 4) * 2 + kk) * 1024 + lane * 16);
            acc[0][0] = __builtin_amdgcn_mfma_f32_16x16x32_f16(a0, bB, acc[0][0], 0, 0, 0);
            acc[0][1] = __builtin_amdgcn_mfma_f32_16x16x32_f16(a0, bC, acc[0][1], 0, 0, 0);
            acc[1][0] = __builtin_amdgcn_mfma_f32_16x16x32_f16(a1, bB, acc[1][0], 0, 0, 0);
            acc[1][1] = __builtin_amdgcn_mfma_f32_16x16x32_f16(a1, bC, acc[1][1], 0, 0, 0);
        }
    }

    // s = sum_n (B+b2)*(C+b3); n = wv*16 + l15 (+ wave pairing over 4 waves)
    float b2v = b2[wv * 16 + l15];
    float b3v = b3[wv * 16 + l15];
#pragma unroll
    for (int m = 0; m < 2; ++m)
#pragma unroll
        for (int r = 0; r < 4; ++r) {
            float p = (acc[m][0][r] + b2v) * (acc[m][1][r] + b3v);
            p += __shfl_xor(p, 1); p += __shfl_xor(p, 2);
            p += __shfl_xor(p, 4); p += __shfl_xor(p, 8);
            if (l15 == 0) sred[wv * 32 + m * 16 + q * 4 + r] = p;
        }
    __syncthreads();
    if (tid < 32)
        s_out[tb + tid] = sred[tid] + sred[32 + tid] + sred[64 + tid] + sred[96 + tid];
}

// ---------------------------------------------------------------------------
// y_kernel: 128 tokens x 64 d per block, K=512, BK=64, double-buffered.
// 512 threads = 8 waves; wave w owns m-tile w x 4 n-tiles.
// Grid (8, 32) = 256 blocks.
// ---------------------------------------------------------------------------
#define Y_BUF 24576   // 16 x-slabs (16KB) + 8 w-slabs (8KB)
__global__ __launch_bounds__(512) void y_kernel(
    const f16* __restrict__ xh, const f16* __restrict__ w1t,
    const float* __restrict__ b1, const float* __restrict__ s_in,
    float* __restrict__ y)
{
    __shared__ __align__(16) char smem[2 * Y_BUF];

    const int tid  = threadIdx.x;
    const int wv   = tid >> 6;          // 0..7 = m-tile
    const int lane = tid & 63;
    const int q    = lane >> 4;
    const int l15  = lane & 15;
    const int db   = blockIdx.x * 64;
    const int tb   = blockIdx.y * 128;

    f32x4 acc[4];
#pragma unroll
    for (int nt = 0; nt < 4; ++nt) acc[nt] = (f32x4){0.f, 0.f, 0.f, 0.f};

    // wave wv stages slabs {3wv, 3wv+1, 3wv+2}
    auto issue = [&](int buf, int kc) {
#pragma unroll
        for (int j = 0; j < 3; ++j) {
            int id = wv * 3 + j;
            const f16* g; int off;
            if (id < 16) {
                int mt = id >> 1, kk = id & 1;
                g = xh + (size_t)(tb + mt * 16 + l15) * DDIM + kc + kk * 32 + q * 8;
                off = id * 1024;
            } else {
                int t = id - 16; int nt = t >> 1, kk = t & 1;
                g = w1t + (size_t)(db + nt * 16 + l15) * DDIM + kc + kk * 32 + q * 8;
                off = 16384 + t * 1024;
            }
            async_load16(g, smem + buf * Y_BUF + off);
        }
    };

    issue(0, 0);
    for (int it = 0; it < 8; ++it) {
        __syncthreads();
        if (it + 1 < 8) issue((it + 1) & 1, (it + 1) * 64);
        const char* xb = smem + (it & 1) * Y_BUF;
        const char* wb = xb + 16384;
#pragma unroll
        for (int kk = 0; kk < 2; ++kk) {
            f16x8 a = *(const f16x8*)(xb + (wv * 2 + kk) * 1024 + lane * 16);
#pragma unroll
            for (int nt = 0; nt < 4; ++nt) {
                f16x8 b = *(const f16x8*)(wb + (nt * 2 + kk) * 1024 + lane * 16);
                acc[nt] = __builtin_amdgcn_mfma_f32_16x16x32_f16(a, b, acc[nt], 0, 0, 0);
            }
        }
    }

    // epilogue: y = x * softplus(acc + b1) * s
    float b1v[4];
#pragma unroll
    for (int nt = 0; nt < 4; ++nt) b1v[nt] = b1[db + nt * 16 + l15];
#pragma unroll
    for (int r = 0; r < 4; ++r) {
        int token = tb + wv * 16 + q * 4 + r;
        float st = s_in[token];
#pragma unroll
        for (int nt = 0; nt < 4; ++nt) {
            int d = db + nt * 16 + l15;
            float xv = (float)xh[(size_t)token * DDIM + d];
            y[(size_t)token * DDIM + d] = xv * softplusf(acc[nt][r] + b1v[nt]) * st;
        }
    }
}

// ---------------------------------------------------------------------------
extern "C" void kernel_launch(void* const* d_in, const int* in_sizes, int n_in,
                              void* d_out, int out_size, void* d_ws, size_t ws_size,
                              hipStream_t stream)
{
    (void)n_in; (void)out_size; (void)ws_size; (void)in_sizes;
    const float* x  = (const float*)d_in[0];
    const float* W1 = (const float*)d_in[1];
    const float* b1 = (const float*)d_in[2];
    const float* W2 = (const float*)d_in[3];
    const float* b2 = (const float*)d_in[4];
    const float* W3 = (const float*)d_in[5];
    const float* b3 = (const float*)d_in[6];
    // d_in[7] = A unused (multiplies h=0)
    float* y = (float*)d_out;

    // workspace layout (16B aligned)
    char* ws  = (char*)d_ws;
    f16* xh   = (f16*)(ws);                          // 4 MB
    f16* w1t  = (f16*)(ws + (4 << 20));              // 512 KB
    f16* w23  = (f16*)(ws + (4 << 20) + (512 << 10)); // 128 KB
    float* sv = (float*)(ws + (5 << 20));            // 16 KB

    prep_kernel<<<2048 + 80, 256, 0, stream>>>(x, W1, W2, W3, xh, w1t, w23);
    s_kernel<<<MTOK / 32, 256, 0, stream>>>(xh, w23, b2, b3, sv);
    y_kernel<<<dim3(DDIM / 64, MTOK / 128), 512, 0, stream>>>(xh, w1t, b1, sv, y);
}

// Round 4
// 97.603 us; speedup vs baseline: 2.7248x; 1.0474x over previous
//
#include <hip/hip_runtime.h>
#include <math.h>

// B=2, L=2048, D=512, N=64 -> M=4096 tokens.
//   y[t,d] = x[t,d] * softplus((x@W1+b1)[t,d]) * s[t]
//   s[t]   = dot(x_t@W2+b2, x_t@W3+b3)
//   exp(delta*A) multiplies h=0 -> contributes zero; A unused.
//
// All GEMM operands are pre-swizzled by prep_kernel into "fragment slabs":
// a slab = one 16(rows)x32(k) f16 MFMA tile stored as 1024 contiguous bytes
// in exact lane order (lane L=q*16+m holds row m, k=q*8..q*8+7).  Main-loop
// global_load_lds then reads 1KB fully contiguous per wave (16 cache lines).
#define DDIM 512
#define MTOK 4096

typedef _Float16 f16;
typedef _Float16 f16x4 __attribute__((ext_vector_type(4)));
typedef _Float16 f16x8 __attribute__((ext_vector_type(8)));
typedef float f32x4 __attribute__((ext_vector_type(4)));

__device__ __forceinline__ float softplusf(float v) {
    return (v > 20.0f) ? v : log1pf(__expf(v));
}

__device__ __forceinline__ void async_load16(const void* g, void* l) {
    __builtin_amdgcn_global_load_lds(
        (const __attribute__((address_space(1))) void*)g,
        (__attribute__((address_space(3))) void*)l, 16, 0, 0);
}

// ---------------------------------------------------------------------------
// prep: 276 blocks x 256 threads.
//  bid<256 : x tile mt  -> xh slabs [mt][kt]          (256*16 slabs)
//  bid 256..271: W1 col-pair p=bid-256 (32 cols) -> w1t slabs [nt][kt], nt=2p,2p+1
//  bid 272..273: W2 cols 32*(bid-272) -> w23 nt {0,1}/{2,3}
//  bid 274..275: W3 cols 32*(bid-274) -> w23 nt {8,9}/{10,11}... (offset 4 nt-units)
// ---------------------------------------------------------------------------
__global__ __launch_bounds__(256) void prep_kernel(
    const float* __restrict__ x,  const float* __restrict__ W1,
    const float* __restrict__ W2, const float* __restrict__ W3,
    f16* __restrict__ xh, f16* __restrict__ w1t, f16* __restrict__ w23)
{
    __shared__ __align__(16) f16 lt[32][520];
    const int tid  = threadIdx.x;
    const int bid  = blockIdx.x;
    const int wv   = tid >> 6;
    const int lane = tid & 63;
    const int q    = lane >> 4;
    const int l15  = lane & 15;

    if (bid < 256) {                              // ---- x tile (16 tokens)
        const int mt  = bid;
        const int row = tid >> 4;
        const int cg  = tid & 15;
        const float* xr = x + (size_t)(mt * 16 + row) * DDIM;
#pragma unroll
        for (int i = 0; i < 8; ++i) {
            int col = cg * 4 + i * 64;
            float4 v = *(const float4*)(xr + col);
            f16x4 h = {(f16)v.x, (f16)v.y, (f16)v.z, (f16)v.w};
            *(f16x4*)&lt[row][col] = h;
        }
        __syncthreads();
#pragma unroll
        for (int j = 0; j < 4; ++j) {
            int kt = wv * 4 + j;
            f16x8 vv = *(const f16x8*)&lt[l15][kt * 32 + q * 8];
            *(f16x8*)(xh + (size_t)(mt * 16 + kt) * 512 + lane * 8) = vv;
        }
        return;
    }
    // ---- weight block: 512 k x 32 cols, transposed -> 32 slabs
    int wb = bid - 256;
    const float* src; int srcRS, col0; f16* dst;
    if (wb < 16)      { src = W1; srcRS = DDIM; col0 = wb * 32;
                        dst = w1t + (size_t)wb * 2 * 16 * 512; }
    else if (wb < 18) { src = W2; srcRS = 64;  col0 = (wb - 16) * 32;
                        dst = w23 + (size_t)(wb - 16) * 2 * 16 * 512; }
    else              { src = W3; srcRS = 64;  col0 = (wb - 18) * 32;
                        dst = w23 + (size_t)(4 + (wb - 18) * 2) * 16 * 512; }
#pragma unroll
    for (int i = 0; i < 16; ++i) {
        int f  = tid + 256 * i;
        int k  = f >> 3;
        int c4 = (f & 7) * 4;
        float4 v = *(const float4*)(src + (size_t)k * srcRS + col0 + c4);
        lt[c4 + 0][k] = (f16)v.x; lt[c4 + 1][k] = (f16)v.y;
        lt[c4 + 2][k] = (f16)v.z; lt[c4 + 3][k] = (f16)v.w;
    }
    __syncthreads();
#pragma unroll
    for (int j = 0; j < 8; ++j) {
        int s   = wv * 8 + j;
        int ntL = s >> 4;          // 0..1
        int kt  = s & 15;
        f16x8 vv = *(const f16x8*)&lt[ntL * 16 + l15][kt * 32 + q * 8];
        *(f16x8*)(dst + (size_t)(ntL * 16 + kt) * 512 + lane * 8) = vv;
    }
}

// ---------------------------------------------------------------------------
// s_kernel: 16 tokens/block, 256 blocks x 256 threads (4 waves).
// Wave wv: B-tile nt=wv, C-tile nt=4+wv (same n columns).  BK=64, dbuf.
// Per iter: 18 slabs (x:2, w23:16).
// ---------------------------------------------------------------------------
#define S_BUF 18432
__global__ __launch_bounds__(256) void s_kernel(
    const f16* __restrict__ xh, const f16* __restrict__ w23,
    const float* __restrict__ b2, const float* __restrict__ b3,
    float* __restrict__ s_out)
{
    __shared__ __align__(16) char smem[2 * S_BUF + 256];
    float* sred = (float*)(smem + 2 * S_BUF);   // [4][16]

    const int tid  = threadIdx.x;
    const int wv   = tid >> 6;
    const int lane = tid & 63;
    const int q    = lane >> 4;
    const int l15  = lane & 15;
    const int mtG  = blockIdx.x;                // 16-token tile index
    const int tb   = mtG * 16;

    f32x4 acc[2];
    acc[0] = (f32x4){0.f, 0.f, 0.f, 0.f};
    acc[1] = (f32x4){0.f, 0.f, 0.f, 0.f};

    auto issue = [&](int buf, int it) {
        int kt0 = it * 2;
#pragma unroll
        for (int j = 0; j < 5; ++j) {
            int id = wv + 4 * j;
            if (id >= 18) break;
            const f16* g; int off;
            if (id < 2) {                       // x slab, kk=id
                g   = xh + (size_t)(mtG * 16 + kt0 + id) * 512 + lane * 8;
                off = id * 1024;
            } else {
                int t = id - 2, nt = t >> 1, kk = t & 1;
                g   = w23 + (size_t)(nt * 16 + kt0 + kk) * 512 + lane * 8;
                off = 2048 + t * 1024;
            }
            async_load16(g, smem + buf * S_BUF + off);
        }
    };

    issue(0, 0);
    for (int it = 0; it < 8; ++it) {
        __syncthreads();
        if (it + 1 < 8) issue((it + 1) & 1, it + 1);
        const char* xb = smem + (it & 1) * S_BUF;
        const char* wb = xb + 2048;
#pragma unroll
        for (int kk = 0; kk < 2; ++kk) {
            f16x8 a  = *(const f16x8*)(xb + kk * 1024 + lane * 16);
            f16x8 bB = *(const f16x8*)(wb + ((wv * 2 + kk)) * 1024 + lane * 16);
            f16x8 bC = *(const f16x8*)(wb + (((4 + wv) * 2 + kk)) * 1024 + lane * 16);
            acc[0] = __builtin_amdgcn_mfma_f32_16x16x32_f16(a, bB, acc[0], 0, 0, 0);
            acc[1] = __builtin_amdgcn_mfma_f32_16x16x32_f16(a, bC, acc[1], 0, 0, 0);
        }
    }

    // s partial: wave wv covers n = wv*16 + l15; token = q*4+r (C/D layout)
    float b2v = b2[wv * 16 + l15];
    float b3v = b3[wv * 16 + l15];
#pragma unroll
    for (int r = 0; r < 4; ++r) {
        float p = (acc[0][r] + b2v) * (acc[1][r] + b3v);
        p += __shfl_xor(p, 1); p += __shfl_xor(p, 2);
        p += __shfl_xor(p, 4); p += __shfl_xor(p, 8);
        if (l15 == 0) sred[wv * 16 + q * 4 + r] = p;
    }
    __syncthreads();
    if (tid < 16)
        s_out[tb + tid] = sred[tid] + sred[16 + tid] + sred[32 + tid] + sred[48 + tid];
}

// ---------------------------------------------------------------------------
// y_kernel: 128 tokens x 64 d per block; grid (8,32), 512 threads (8 waves).
// Wave wv owns m-tile wv x 4 n-tiles.  BK=64, dbuf.  Per iter: 24 slabs.
// ---------------------------------------------------------------------------
#define Y_BUF 24576
__global__ __launch_bounds__(512) void y_kernel(
    const f16* __restrict__ xh, const f16* __restrict__ w1t,
    const float* __restrict__ x, const float* __restrict__ b1,
    const float* __restrict__ s_in, float* __restrict__ y)
{
    __shared__ __align__(16) char smem[2 * Y_BUF];

    const int tid  = threadIdx.x;
    const int wv   = tid >> 6;
    const int lane = tid & 63;
    const int q    = lane >> 4;
    const int l15  = lane & 15;
    const int db   = blockIdx.x * 64;           // d-block
    const int ntG  = blockIdx.x * 4;            // first w1t n-tile
    const int tb   = blockIdx.y * 128;          // token block
    const int mtG  = blockIdx.y * 8;            // first xh m-tile

    f32x4 acc[4];
#pragma unroll
    for (int nt = 0; nt < 4; ++nt) acc[nt] = (f32x4){0.f, 0.f, 0.f, 0.f};

    auto issue = [&](int buf, int it) {
        int kt0 = it * 2;
#pragma unroll
        for (int j = 0; j < 3; ++j) {
            int id = wv * 3 + j;
            const f16* g; int off;
            if (id < 16) {
                int mt = id >> 1, kk = id & 1;
                g   = xh + (size_t)((mtG + mt) * 16 + kt0 + kk) * 512 + lane * 8;
                off = id * 1024;
            } else {
                int t = id - 16, nt = t >> 1, kk = t & 1;
                g   = w1t + (size_t)((ntG + nt) * 16 + kt0 + kk) * 512 + lane * 8;
                off = 16384 + t * 1024;
            }
            async_load16(g, smem + buf * Y_BUF + off);
        }
    };

    issue(0, 0);
    for (int it = 0; it < 8; ++it) {
        __syncthreads();
        if (it + 1 < 8) issue((it + 1) & 1, it + 1);
        const char* xb = smem + (it & 1) * Y_BUF;
        const char* wb = xb + 16384;
#pragma unroll
        for (int kk = 0; kk < 2; ++kk) {
            f16x8 a = *(const f16x8*)(xb + (wv * 2 + kk) * 1024 + lane * 16);
#pragma unroll
            for (int nt = 0; nt < 4; ++nt) {
                f16x8 b = *(const f16x8*)(wb + (nt * 2 + kk) * 1024 + lane * 16);
                acc[nt] = __builtin_amdgcn_mfma_f32_16x16x32_f16(a, b, acc[nt], 0, 0, 0);
            }
        }
    }

    // epilogue: y = x_fp32 * softplus(acc + b1) * s
    float b1v[4];
#pragma unroll
    for (int nt = 0; nt < 4; ++nt) b1v[nt] = b1[db + nt * 16 + l15];
#pragma unroll
    for (int r = 0; r < 4; ++r) {
        int token = tb + wv * 16 + q * 4 + r;
        float st = s_in[token];
#pragma unroll
        for (int nt = 0; nt < 4; ++nt) {
            int d = db + nt * 16 + l15;
            float xv = x[(size_t)token * DDIM + d];
            y[(size_t)token * DDIM + d] = xv * softplusf(acc[nt][r] + b1v[nt]) * st;
        }
    }
}

// ---------------------------------------------------------------------------
extern "C" void kernel_launch(void* const* d_in, const int* in_sizes, int n_in,
                              void* d_out, int out_size, void* d_ws, size_t ws_size,
                              hipStream_t stream)
{
    (void)n_in; (void)out_size; (void)ws_size; (void)in_sizes;
    const float* x  = (const float*)d_in[0];
    const float* W1 = (const float*)d_in[1];
    const float* b1 = (const float*)d_in[2];
    const float* W2 = (const float*)d_in[3];
    const float* b2 = (const float*)d_in[4];
    const float* W3 = (const float*)d_in[5];
    const float* b3 = (const float*)d_in[6];
    // d_in[7] = A unused (multiplies h=0)
    float* y = (float*)d_out;

    char* ws  = (char*)d_ws;
    f16* xh   = (f16*)(ws);                           // 4 MB  (256*16 slabs)
    f16* w1t  = (f16*)(ws + (4 << 20));               // 512 KB (32*16 slabs)
    f16* w23  = (f16*)(ws + (4 << 20) + (512 << 10)); // 128 KB (8*16 slabs)
    float* sv = (float*)(ws + (5 << 20));             // 16 KB

    prep_kernel<<<276, 256, 0, stream>>>(x, W1, W2, W3, xh, w1t, w23);
    s_kernel<<<MTOK / 16, 256, 0, stream>>>(xh, w23, b2, b3, sv);
    y_kernel<<<dim3(DDIM / 64, MTOK / 128), 512, 0, stream>>>(xh, w1t, x, b1, sv, y);
}

// Round 5
// 94.633 us; speedup vs baseline: 2.8104x; 1.0314x over previous
//
#include <hip/hip_runtime.h>
#include <math.h>

// B=2, L=2048, D=512, N=64 -> M=4096 tokens.
//   y[t,d] = x[t,d] * softplus((x@W1+b1)[t,d]) * s[t]
//   s[t]   = dot(x_t@W2+b2, x_t@W3+b3)
//   exp(delta*A) multiplies h=0 -> contributes zero; A unused.
//
// Operands pre-swizzled into MFMA "fragment slabs": one 16(rows)x32(k) f16
// tile = 1024 contiguous bytes in exact lane order (lane L=q*16+m holds row m,
// k=q*8..q*8+7).  GEMM fragments then load DIRECTLY global->VGPR as fully
// coalesced 1KB wave reads (L2-hot) -- no LDS staging, no barriers in y.
#define DDIM 512

typedef _Float16 f16;
typedef _Float16 f16x4 __attribute__((ext_vector_type(4)));
typedef _Float16 f16x8 __attribute__((ext_vector_type(8)));
typedef float f32x4 __attribute__((ext_vector_type(4)));

__device__ __forceinline__ float softplusf(float v) {
    return (v > 20.0f) ? v : log1pf(__expf(v));
}

// ---------------------------------------------------------------------------
// prep_w: 20 blocks x 256 thr.  W1 -> w1t slabs (nt 0..31); W2 -> w23 nt 0..3;
// W3 -> w23 nt 4..7.  Each block transposes a 512k x 32col strip.
// ---------------------------------------------------------------------------
__global__ __launch_bounds__(256) void prep_w(
    const float* __restrict__ W1, const float* __restrict__ W2,
    const float* __restrict__ W3, f16* __restrict__ w1t, f16* __restrict__ w23)
{
    __shared__ __align__(16) f16 lt[32][520];
    const int tid  = threadIdx.x;
    const int wb   = blockIdx.x;
    const int wv   = tid >> 6;
    const int lane = tid & 63;
    const int q    = lane >> 4;
    const int l15  = lane & 15;

    const float* src; int srcRS, col0; f16* dst;
    if (wb < 16)      { src = W1; srcRS = DDIM; col0 = wb * 32;
                        dst = w1t + (size_t)wb * 2 * 16 * 512; }
    else if (wb < 18) { src = W2; srcRS = 64;  col0 = (wb - 16) * 32;
                        dst = w23 + (size_t)(wb - 16) * 2 * 16 * 512; }
    else              { src = W3; srcRS = 64;  col0 = (wb - 18) * 32;
                        dst = w23 + (size_t)(4 + (wb - 18) * 2) * 16 * 512; }
#pragma unroll
    for (int i = 0; i < 16; ++i) {
        int f  = tid + 256 * i;
        int k  = f >> 3;
        int c4 = (f & 7) * 4;
        float4 v = *(const float4*)(src + (size_t)k * srcRS + col0 + c4);
        lt[c4 + 0][k] = (f16)v.x; lt[c4 + 1][k] = (f16)v.y;
        lt[c4 + 2][k] = (f16)v.z; lt[c4 + 3][k] = (f16)v.w;
    }
    __syncthreads();
#pragma unroll
    for (int j = 0; j < 8; ++j) {
        int s   = wv * 8 + j;          // 0..31
        int ntL = s >> 4;              // 0..1
        int kt  = s & 15;
        f16x8 vv = *(const f16x8*)&lt[ntL * 16 + l15][kt * 32 + q * 8];
        *(f16x8*)(dst + (size_t)(ntL * 16 + kt) * 512 + lane * 8) = vv;
    }
}

// ---------------------------------------------------------------------------
// s_kernel: 256 blocks x 256 thr (4 waves), 16 tokens/block.
// Converts x->f16 (LDS staged, also written to xh slabs for y_kernel);
// w23 B-fragments load direct global->VGPR.  One barrier total.
// Wave wv: B at nt=wv, C at nt=4+wv.
// ---------------------------------------------------------------------------
__global__ __launch_bounds__(256) void s_kernel(
    const float* __restrict__ x, const f16* __restrict__ w23,
    const float* __restrict__ b2, const float* __restrict__ b3,
    f16* __restrict__ xh, float* __restrict__ s_out)
{
    __shared__ __align__(16) f16 xs[16][520];
    __shared__ float sred[64];

    const int tid  = threadIdx.x;
    const int wv   = tid >> 6;
    const int lane = tid & 63;
    const int q    = lane >> 4;
    const int l15  = lane & 15;
    const int mtG  = blockIdx.x;
    const int tb   = mtG * 16;

    // stage x: row=tid>>4, 8 strided float4 reads, convert, LDS write
    {
        const int row = tid >> 4, cg = tid & 15;
        const float* xr = x + (size_t)(tb + row) * DDIM;
#pragma unroll
        for (int i = 0; i < 8; ++i) {
            int col = cg * 4 + i * 64;
            float4 v = *(const float4*)(xr + col);
            f16x4 h = {(f16)v.x, (f16)v.y, (f16)v.z, (f16)v.w};
            *(f16x4*)&xs[row][col] = h;
        }
    }
    __syncthreads();

    // write xh fragment slabs (for y_kernel) while compute proceeds
#pragma unroll
    for (int j = 0; j < 4; ++j) {
        int kt = wv * 4 + j;
        f16x8 vv = *(const f16x8*)&xs[l15][kt * 32 + q * 8];
        *(f16x8*)(xh + (size_t)(mtG * 16 + kt) * 512 + lane * 8) = vv;
    }

    f32x4 acc0 = (f32x4){0.f, 0.f, 0.f, 0.f};
    f32x4 acc1 = (f32x4){0.f, 0.f, 0.f, 0.f};
    const f16* wB = w23 + (size_t)(wv    ) * 16 * 512 + lane * 8;
    const f16* wC = w23 + (size_t)(wv + 4) * 16 * 512 + lane * 8;
#pragma unroll
    for (int kt = 0; kt < 16; ++kt) {
        f16x8 a  = *(const f16x8*)&xs[l15][kt * 32 + q * 8];
        f16x8 bB = *(const f16x8*)(wB + (size_t)kt * 512);
        f16x8 bC = *(const f16x8*)(wC + (size_t)kt * 512);
        acc0 = __builtin_amdgcn_mfma_f32_16x16x32_f16(a, bB, acc0, 0, 0, 0);
        acc1 = __builtin_amdgcn_mfma_f32_16x16x32_f16(a, bC, acc1, 0, 0, 0);
    }

    // s partial over n = wv*16 + l15 ; token = q*4 + r
    float b2v = b2[wv * 16 + l15];
    float b3v = b3[wv * 16 + l15];
#pragma unroll
    for (int r = 0; r < 4; ++r) {
        float p = (acc0[r] + b2v) * (acc1[r] + b3v);
        p += __shfl_xor(p, 1); p += __shfl_xor(p, 2);
        p += __shfl_xor(p, 4); p += __shfl_xor(p, 8);
        if (l15 == 0) sred[wv * 16 + q * 4 + r] = p;
    }
    __syncthreads();
    if (tid < 16)
        s_out[tb + tid] = sred[tid] + sred[16 + tid] + sred[32 + tid] + sred[48 + tid];
}

// ---------------------------------------------------------------------------
// y_kernel: zero-LDS register GEMM.  Grid (8, M/64) x 512 thr (8 waves),
// 2 blocks/CU.  Wave wv: m-tile mt=wv&3 (16 tokens), n-tiles nh*2, nh*2+1.
// All fragments load direct global->VGPR from pre-swizzled slabs (L2-hot).
// ---------------------------------------------------------------------------
__global__ __launch_bounds__(512) void y_kernel(
    const f16* __restrict__ xh, const f16* __restrict__ w1t,
    const float* __restrict__ x, const float* __restrict__ b1,
    const float* __restrict__ s_in, float* __restrict__ y)
{
    const int tid  = threadIdx.x;
    const int wv   = tid >> 6;
    const int lane = tid & 63;
    const int q    = lane >> 4;
    const int l15  = lane & 15;
    const int mt   = wv & 3;
    const int nh   = wv >> 2;
    const int cB   = blockIdx.x;          // d-block (64 cols)
    const int rB   = blockIdx.y;          // token-block (64 rows)

    const f16* aP  = xh  + (size_t)((rB * 4 + mt) * 16) * 512 + lane * 8;
    const f16* bP0 = w1t + (size_t)((cB * 4 + nh * 2 + 0) * 16) * 512 + lane * 8;
    const f16* bP1 = w1t + (size_t)((cB * 4 + nh * 2 + 1) * 16) * 512 + lane * 8;

    f32x4 acc0 = (f32x4){0.f, 0.f, 0.f, 0.f};
    f32x4 acc1 = (f32x4){0.f, 0.f, 0.f, 0.f};
#pragma unroll
    for (int kt = 0; kt < 16; ++kt) {
        f16x8 a  = *(const f16x8*)(aP  + (size_t)kt * 512);
        f16x8 b0 = *(const f16x8*)(bP0 + (size_t)kt * 512);
        f16x8 b1v = *(const f16x8*)(bP1 + (size_t)kt * 512);
        acc0 = __builtin_amdgcn_mfma_f32_16x16x32_f16(a, b0,  acc0, 0, 0, 0);
        acc1 = __builtin_amdgcn_mfma_f32_16x16x32_f16(a, b1v, acc1, 0, 0, 0);
    }

    // epilogue: y = x_fp32 * softplus(acc + b1) * s
    const int d0 = cB * 64 + (nh * 2 + 0) * 16 + l15;
    const int d1 = cB * 64 + (nh * 2 + 1) * 16 + l15;
    const float bb0 = b1[d0], bb1 = b1[d1];
#pragma unroll
    for (int r = 0; r < 4; ++r) {
        int token = rB * 64 + mt * 16 + q * 4 + r;
        float st = s_in[token];
        const float* xr = x + (size_t)token * DDIM;
        float*       yr = y + (size_t)token * DDIM;
        yr[d0] = xr[d0] * softplusf(acc0[r] + bb0) * st;
        yr[d1] = xr[d1] * softplusf(acc1[r] + bb1) * st;
    }
}

// ---------------------------------------------------------------------------
extern "C" void kernel_launch(void* const* d_in, const int* in_sizes, int n_in,
                              void* d_out, int out_size, void* d_ws, size_t ws_size,
                              hipStream_t stream)
{
    (void)n_in; (void)out_size; (void)ws_size;
    const float* x  = (const float*)d_in[0];
    const float* W1 = (const float*)d_in[1];
    const float* b1 = (const float*)d_in[2];
    const float* W2 = (const float*)d_in[3];
    const float* b2 = (const float*)d_in[4];
    const float* W3 = (const float*)d_in[5];
    const float* b3 = (const float*)d_in[6];
    // d_in[7] = A unused (multiplies h=0)
    float* y = (float*)d_out;

    char* ws  = (char*)d_ws;
    f16* xh   = (f16*)(ws);                           // 4 MB   (M/16 x 16 slabs)
    f16* w1t  = (f16*)(ws + (4 << 20));               // 512 KB (32 nt x 16 kt)
    f16* w23  = (f16*)(ws + (4 << 20) + (512 << 10)); // 128 KB (8 nt x 16 kt)
    float* sv = (float*)(ws + (5 << 20));             // 16 KB

    const int M = in_sizes[0] / DDIM;                 // 4096

    prep_w<<<20, 256, 0, stream>>>(W1, W2, W3, w1t, w23);
    s_kernel<<<M / 16, 256, 0, stream>>>(x, w23, b2, b3, xh, sv);
    y_kernel<<<dim3(8, M / 64), 512, 0, stream>>>(xh, w1t, x, b1, sv, y);
}